// Round 2
// baseline (1875.619 us; speedup 1.0000x reference)
//
#include <hip/hip_runtime.h>
#include <hip/hip_bf16.h>

#define Bn 4
#define Cn 64
#define Hn 128
#define Wn 128
#define On 64
#define DGn 2
#define Cgn 32
#define HWn (Hn*Wn)

// ws layout (floats):
//   off   : [B][36][H][W]   @ 0
//   wtdef : [2][9][32][64]  @ OFF_FLOATS      (dst [g][k][c][o])
//   wtoff : [64][9][36]     @ +WTDEF_FLOATS   (dst [c][k][j])
#define OFF_FLOATS   (Bn*36*HWn)
#define WTDEF_FLOATS (2*9*32*64)
#define WTOFF_FLOATS (64*9*36)

__global__ __launch_bounds__(256) void prep_weights(const float* __restrict__ w_off,
                                                    const float* __restrict__ w_def,
                                                    float* __restrict__ wtdef,
                                                    float* __restrict__ wtoff) {
  int t = blockIdx.x * 256 + threadIdx.x;
  if (t < WTDEF_FLOATS) {
    int o = t & 63;
    int c = (t >> 6) & 31;
    int r = t >> 11;         // g*9 + k
    int k = r % 9;
    int g = r / 9;
    wtdef[t] = w_def[(o * Cn + g * Cgn + c) * 9 + k];
  }
  if (t < WTOFF_FLOATS) {
    int j = t % 36;
    int k = (t / 36) % 9;
    int c = t / 324;
    wtoff[t] = w_off[(j * Cn + c) * 9 + k];
  }
}

// Offset conv, 4-way channel split per pixel. grid = B*HW*4/256 = 1024 blocks.
__global__ __launch_bounds__(256, 4) void offs_conv(const float* __restrict__ x,
                                                    const float* __restrict__ wtoff,
                                                    float* __restrict__ off) {
  const int t = blockIdx.x * 256 + threadIdx.x;
  const int split = t & 3;            // lanes 4p..4p+3 share a pixel
  const int pixid = t >> 2;
  const int w = pixid & (Wn - 1);
  const int h = (pixid >> 7) & (Hn - 1);
  const int b = pixid >> 14;
  const int pix = h * Wn + w;

  float acc[36];
#pragma unroll
  for (int j = 0; j < 36; ++j) acc[j] = 0.f;

  const float* xb = x + b * Cn * HWn;

  const int c0 = split * 16;
#pragma unroll 2
  for (int cc = 0; cc < 16; ++cc) {
    const int c = c0 + cc;
    const float* xc = xb + c * HWn;
    float xv[9];
#pragma unroll
    for (int kh = 0; kh < 3; ++kh) {
#pragma unroll
      for (int kw = 0; kw < 3; ++kw) {
        int hh = h + kh - 1, ww = w + kw - 1;
        bool v = (hh >= 0) && (hh < Hn) && (ww >= 0) && (ww < Wn);
        int hc = min(max(hh, 0), Hn - 1);
        int wc = min(max(ww, 0), Wn - 1);
        float val = xc[hc * Wn + wc];
        xv[kh * 3 + kw] = v ? val : 0.f;
      }
    }
    const float* wc = wtoff + c * 324;   // [k][j], wave-uniform -> s_load
#pragma unroll
    for (int k = 0; k < 9; ++k) {
#pragma unroll
      for (int j = 0; j < 36; ++j)
        acc[j] = fmaf(xv[k], wc[k * 36 + j], acc[j]);
    }
  }

  // butterfly reduce across the 4 split-lanes (same pixel)
#pragma unroll
  for (int j = 0; j < 36; ++j) acc[j] += __shfl_xor(acc[j], 1);
#pragma unroll
  for (int j = 0; j < 36; ++j) acc[j] += __shfl_xor(acc[j], 2);

  // each lane writes its 9 of the 36 offset channels
  float* op = off + b * 36 * HWn + pix;
#pragma unroll
  for (int jj = 0; jj < 9; ++jj) {
    int j = split * 9 + jj;
    op[j * HWn] = acc[j];
  }
}

// Deformable gather + projection, 4-way channel split per pixel.
__global__ __launch_bounds__(256, 4) void deform_main(const float* __restrict__ x,
                                                      const float* __restrict__ wtdef,
                                                      const float* __restrict__ off,
                                                      float* __restrict__ out) {
  const int t = blockIdx.x * 256 + threadIdx.x;
  const int split = t & 3;
  const int pixid = t >> 2;
  const int w = pixid & (Wn - 1);
  const int h = (pixid >> 7) & (Hn - 1);
  const int b = pixid >> 14;
  const int pix = h * Wn + w;

  const float* offp = off + b * 36 * HWn + pix;

  float acc[On];
#pragma unroll
  for (int o = 0; o < On; ++o) acc[o] = 0.f;

  for (int g = 0; g < DGn; ++g) {
    const float* xg = x + (b * Cn + g * Cgn) * HWn;
    for (int k = 0; k < 9; ++k) {
      float ody = offp[(g * 18 + k * 2 + 0) * HWn];
      float odx = offp[(g * 18 + k * 2 + 1) * HWn];
      float py = ody + (float)(h + k / 3 - 1);
      float px = odx + (float)(w + k % 3 - 1);
      float fy = floorf(py), fx = floorf(px);
      int y0 = (int)fy, x0 = (int)fx;
      float dy = py - fy, dx = px - fx;

      bool vy0 = (y0 >= 0) && (y0 < Hn);
      bool vy1 = (y0 >= -1) && (y0 < Hn - 1);
      bool vx0 = (x0 >= 0) && (x0 < Wn);
      bool vx1 = (x0 >= -1) && (x0 < Wn - 1);
      float omdy = 1.f - dy, omdx = 1.f - dx;
      float w00 = (vy0 && vx0) ? omdy * omdx : 0.f;
      float w01 = (vy0 && vx1) ? omdy * dx   : 0.f;
      float w10 = (vy1 && vx0) ? dy * omdx   : 0.f;
      float w11 = (vy1 && vx1) ? dy * dx     : 0.f;

      int iy0 = min(max(y0, 0), Hn - 1), iy1 = min(max(y0 + 1, 0), Hn - 1);
      int ix0 = min(max(x0, 0), Wn - 1), ix1 = min(max(x0 + 1, 0), Wn - 1);
      int b00 = iy0 * Wn + ix0, b01 = iy0 * Wn + ix1;
      int b10 = iy1 * Wn + ix0, b11 = iy1 * Wn + ix1;

      const float* wgk = wtdef + (g * 9 + k) * Cgn * On;  // [c][o]
      const int c0 = split * 8;
#pragma unroll
      for (int cc = 0; cc < 8; ++cc) {
        const int c = c0 + cc;
        const float* xc = xg + c * HWn;
        float val =       w00 * xc[b00];
        val = fmaf(w01, xc[b01], val);
        val = fmaf(w10, xc[b10], val);
        val = fmaf(w11, xc[b11], val);
        const float* wv = wgk + c * On;
#pragma unroll
        for (int o = 0; o < On; ++o)
          acc[o] = fmaf(val, wv[o], acc[o]);   // wave-uniform -> s_load
      }
    }
  }

  // reduce partial acc across the 4 split-lanes
#pragma unroll
  for (int o = 0; o < On; ++o) acc[o] += __shfl_xor(acc[o], 1);
#pragma unroll
  for (int o = 0; o < On; ++o) acc[o] += __shfl_xor(acc[o], 2);

  // each lane writes its 16 of the 64 output channels
  float* outp = out + b * On * HWn + pix;
#pragma unroll
  for (int oo = 0; oo < 16; ++oo) {
    int o = split * 16 + oo;
    outp[o * HWn] = acc[o];
  }
}

extern "C" void kernel_launch(void* const* d_in, const int* in_sizes, int n_in,
                              void* d_out, int out_size, void* d_ws, size_t ws_size,
                              hipStream_t stream) {
  const float* x     = (const float*)d_in[0];
  const float* w_off = (const float*)d_in[1];
  const float* w_def = (const float*)d_in[2];
  float* out = (float*)d_out;

  float* ws    = (float*)d_ws;
  float* off   = ws;
  float* wtdef = ws + OFF_FLOATS;
  float* wtoff = wtdef + WTDEF_FLOATS;

  prep_weights<<<(WTDEF_FLOATS + 255) / 256, 256, 0, stream>>>(w_off, w_def, wtdef, wtoff);
  offs_conv<<<(Bn * HWn * 4) / 256, 256, 0, stream>>>(x, wtoff, off);
  deform_main<<<(Bn * HWn * 4) / 256, 256, 0, stream>>>(x, wtdef, off, out);
}

// Round 3
// 84.630 us; speedup vs baseline: 22.1626x; 22.1626x over previous
//
#include <hip/hip_runtime.h>
#include <hip/hip_bf16.h>

typedef short bf16x8 __attribute__((ext_vector_type(8)));
typedef float f32x4  __attribute__((ext_vector_type(4)));

#define Bn 4
#define Cn 64
#define Hn 128
#define Wn 128
#define On 64
#define HWn 16384

// ws layout (bytes):
//   xt     [B][H][W][C] bf16   @ 0                  (8,388,608)
//   off    [B][36][H][W] f32   @ XT_BYTES           (9,437,184)
//   pk_def [18][4][64][8] bf16 @ XT+OFF             (147,456)   B-frags, main conv
//   pk_off [18][3][64][8] bf16 @ XT+OFF+PKDEF       (55,296)    B-frags, offset conv
#define XT_BYTES    (Bn*HWn*Cn*2)
#define OFF_BYTES   (Bn*36*HWn*4)
#define PKDEF_BYTES (18*4*64*8*2)

static __device__ __forceinline__ unsigned pk_bf16(float lo, float hi) {
  union { __hip_bfloat162 h; unsigned u; } cv;
  cv.h = __float22bfloat162_rn(make_float2(lo, hi));
  return cv.u;
}
static __device__ __forceinline__ float blo(unsigned u) { return __uint_as_float(u << 16); }
static __device__ __forceinline__ float bhi(unsigned u) { return __uint_as_float(u & 0xffff0000u); }

// ---- x: NCHW f32 -> NHWC bf16, LDS-tiled transpose (64 pix x 64 ch per block)
__global__ __launch_bounds__(256) void transpose_cast(const float* __restrict__ x,
                                                      ushort* __restrict__ xt) {
  __shared__ float tile[64][65];
  const int t = threadIdx.x;
  const int blk = blockIdx.x;            // 1024 = B * (HW/64)
  const int b = blk >> 8;
  const int pix0 = (blk & 255) * 64;
  const float* xb = x + (b * Cn) * HWn + pix0;
#pragma unroll
  for (int q = 0; q < 16; ++q) {
    int idx = q * 256 + t;
    int c = idx >> 6, p = idx & 63;      // lanes: consecutive p, fixed c -> coalesced
    tile[c][p] = xb[c * HWn + p];
  }
  __syncthreads();
  const int p = t >> 2, cg = t & 3;
  unsigned u[8];
#pragma unroll
  for (int j = 0; j < 8; ++j)
    u[j] = pk_bf16(tile[cg * 16 + 2 * j][p], tile[cg * 16 + 2 * j + 1][p]);
  ushort* dst = xt + ((b * HWn + pix0 + p) * 64 + cg * 16);
  uint4 v0 = {u[0], u[1], u[2], u[3]}, v1 = {u[4], u[5], u[6], u[7]};
  *(uint4*)dst = v0;
  *(uint4*)(dst + 8) = v1;
}

// ---- pack weights as MFMA B-fragments (K-slice = 32 channels)
// pk_def slice s=g*9+k: B[c=(lane>>4)*8+j][o=oc*16+(lane&15)] = w_def[o][g*32+c][k]
// pk_off slice s=k*2+ch: B[c'=(lane>>4)*8+j][j_out]           = w_off[j_out][ch*32+c'][k]
__global__ __launch_bounds__(256) void prep_pack(const float* __restrict__ w_off,
                                                 const float* __restrict__ w_def,
                                                 ushort* __restrict__ pk_def,
                                                 ushort* __restrict__ pk_off) {
  const int t = blockIdx.x * 256 + threadIdx.x;
  if (t < 4608) {                        // 18*4*64
    int lane = t & 63, oc = (t >> 6) & 3, s = t >> 8;
    int g = s / 9, k = s % 9;
    int o = oc * 16 + (lane & 15);
    int cb = g * 32 + (lane >> 4) * 8;
    unsigned u[4];
#pragma unroll
    for (int j = 0; j < 4; ++j)
      u[j] = pk_bf16(w_def[(o * Cn + cb + 2 * j) * 9 + k],
                     w_def[(o * Cn + cb + 2 * j + 1) * 9 + k]);
    uint4 v = {u[0], u[1], u[2], u[3]};
    *(uint4*)(pk_def + t * 8) = v;
  } else if (t < 8064) {                 // + 18*3*64
    int t2 = t - 4608;
    int lane = t2 & 63, r = t2 >> 6;     // r = s*3 + oc
    int oc = r % 3, s = r / 3;
    int k = s >> 1, chalf = s & 1;
    int o = oc * 16 + (lane & 15);
    int cb = chalf * 32 + (lane >> 4) * 8;
    unsigned u[4];
#pragma unroll
    for (int j = 0; j < 4; ++j) {
      float lo = (o < 36) ? w_off[(o * Cn + cb + 2 * j) * 9 + k] : 0.f;
      float hi = (o < 36) ? w_off[(o * Cn + cb + 2 * j + 1) * 9 + k] : 0.f;
      u[j] = pk_bf16(lo, hi);
    }
    uint4 v = {u[0], u[1], u[2], u[3]};
    *(uint4*)(pk_off + (r * 64 + lane) * 8) = v;
  }
}

// ---- offset conv via MFMA: M=16 pix/wave, N=48 (36 used), K=576 (k,c)
__global__ __launch_bounds__(512, 4) void offs_conv_mfma(const ushort* __restrict__ xt,
                                                         const ushort* __restrict__ pk_off,
                                                         float* __restrict__ off) {
  const int lane = threadIdx.x & 63;
  const int wid = threadIdx.x >> 6;
  const int gp0 = blockIdx.x * 128 + wid * 16;   // 16 consecutive pixels / wave
  const int b = gp0 >> 14;
  const int pixin = gp0 & 16383;
  const int h = pixin >> 7;
  const int p = lane & 15, kq = lane >> 4;
  const int w_ = (pixin & 127) + p;

  f32x4 acc0 = {0,0,0,0}, acc1 = {0,0,0,0}, acc2 = {0,0,0,0};
  const bf16x8* pB = (const bf16x8*)pk_off;

#pragma unroll
  for (int k = 0; k < 9; ++k) {
    const int ky = k / 3 - 1, kx = k % 3 - 1;
    int y = h + ky, xx = w_ + kx;
    bool valid = ((unsigned)y < 128u) && ((unsigned)xx < 128u);
    int yc = min(max(y, 0), 127), xc = min(max(xx, 0), 127);
    const ushort* src = xt + (((b << 14) + (yc << 7) + xc) << 6) + kq * 8;
#pragma unroll
    for (int chalf = 0; chalf < 2; ++chalf) {
      uint4 av = *(const uint4*)(src + chalf * 32);
      if (!valid) { av.x = 0; av.y = 0; av.z = 0; av.w = 0; }
      union { uint4 u; bf16x8 v; } A; A.u = av;
      int s = k * 2 + chalf;
      acc0 = __builtin_amdgcn_mfma_f32_16x16x32_bf16(A.v, pB[(s*3 + 0)*64 + lane], acc0, 0,0,0);
      acc1 = __builtin_amdgcn_mfma_f32_16x16x32_bf16(A.v, pB[(s*3 + 1)*64 + lane], acc1, 0,0,0);
      acc2 = __builtin_amdgcn_mfma_f32_16x16x32_bf16(A.v, pB[(s*3 + 2)*64 + lane], acc2, 0,0,0);
    }
  }
  // D: col = oc*16 + (lane&15), row(pixel) = (lane>>4)*4 + r
  float* ob = off + pixin + kq * 4;
  const int colb = lane & 15;
#pragma unroll
  for (int r = 0; r < 4; ++r) {
    ob[((b*36 +      colb) << 14) + r] = acc0[r];
    ob[((b*36 + 16 + colb) << 14) + r] = acc1[r];
    if (colb < 4) ob[((b*36 + 32 + colb) << 14) + r] = acc2[r];
  }
}

// ---- main deformable conv via MFMA: M=16 pix/wave, N=64, K=576 (g,k,c)
__global__ __launch_bounds__(512, 4) void deform_main_mfma(const ushort* __restrict__ xt,
                                                           const ushort* __restrict__ pk_def,
                                                           const float* __restrict__ off,
                                                           float* __restrict__ out) {
  const int lane = threadIdx.x & 63;
  const int wid = threadIdx.x >> 6;
  const int gp0 = blockIdx.x * 128 + wid * 16;
  const int b = gp0 >> 14;
  const int pixin = gp0 & 16383;
  const int h = pixin >> 7;
  const int p = lane & 15, kq = lane >> 4;
  const int w_ = (pixin & 127) + p;

  f32x4 acc0={0,0,0,0}, acc1={0,0,0,0}, acc2={0,0,0,0}, acc3={0,0,0,0};
  const bf16x8* pB = (const bf16x8*)pk_def;
  const float* offb = off + ((b * 36) << 14) + pixin + p;
  const int imgb = b << 14;

  for (int g = 0; g < 2; ++g) {
    const int cb = g * 32 + kq * 8;
#pragma unroll
    for (int k = 0; k < 9; ++k) {
      const int s = g * 9 + k;
      float ody = offb[(2 * s) << 14];
      float odx = offb[(2 * s + 1) << 14];
      float py = ody + (float)(h + k / 3 - 1);
      float px = odx + (float)(w_ + k % 3 - 1);
      float fy = floorf(py), fx = floorf(px);
      int y0 = (int)fy, x0 = (int)fx;
      float dy = py - fy, dx = px - fx;

      bool vy0 = (y0 >= 0) && (y0 < Hn);
      bool vy1 = (y0 >= -1) && (y0 < Hn - 1);
      bool vx0 = (x0 >= 0) && (x0 < Wn);
      bool vx1 = (x0 >= -1) && (x0 < Wn - 1);
      float omdy = 1.f - dy, omdx = 1.f - dx;
      float w00 = (vy0 && vx0) ? omdy * omdx : 0.f;
      float w01 = (vy0 && vx1) ? omdy * dx   : 0.f;
      float w10 = (vy1 && vx0) ? dy * omdx   : 0.f;
      float w11 = (vy1 && vx1) ? dy * dx     : 0.f;

      int iy0 = min(max(y0, 0), Hn - 1), iy1 = min(max(y0 + 1, 0), Hn - 1);
      int ix0 = min(max(x0, 0), Wn - 1), ix1 = min(max(x0 + 1, 0), Wn - 1);
      int rb0 = imgb + (iy0 << 7), rb1 = imgb + (iy1 << 7);

      uint4 c00 = *(const uint4*)(xt + ((rb0 + ix0) << 6) + cb);
      uint4 c01 = *(const uint4*)(xt + ((rb0 + ix1) << 6) + cb);
      uint4 c10 = *(const uint4*)(xt + ((rb1 + ix0) << 6) + cb);
      uint4 c11 = *(const uint4*)(xt + ((rb1 + ix1) << 6) + cb);

      unsigned au[4];
#define BILC(comp, idx)                                                          \
      { float l = w00 * blo(c00.comp); l = fmaf(w01, blo(c01.comp), l);          \
        l = fmaf(w10, blo(c10.comp), l); l = fmaf(w11, blo(c11.comp), l);        \
        float hh = w00 * bhi(c00.comp); hh = fmaf(w01, bhi(c01.comp), hh);       \
        hh = fmaf(w10, bhi(c10.comp), hh); hh = fmaf(w11, bhi(c11.comp), hh);    \
        au[idx] = pk_bf16(l, hh); }
      BILC(x, 0) BILC(y, 1) BILC(z, 2) BILC(w, 3)
#undef BILC
      union { uint4 u; bf16x8 v; } A;
      A.u.x = au[0]; A.u.y = au[1]; A.u.z = au[2]; A.u.w = au[3];

      acc0 = __builtin_amdgcn_mfma_f32_16x16x32_bf16(A.v, pB[(s*4 + 0)*64 + lane], acc0, 0,0,0);
      acc1 = __builtin_amdgcn_mfma_f32_16x16x32_bf16(A.v, pB[(s*4 + 1)*64 + lane], acc1, 0,0,0);
      acc2 = __builtin_amdgcn_mfma_f32_16x16x32_bf16(A.v, pB[(s*4 + 2)*64 + lane], acc2, 0,0,0);
      acc3 = __builtin_amdgcn_mfma_f32_16x16x32_bf16(A.v, pB[(s*4 + 3)*64 + lane], acc3, 0,0,0);
    }
  }

  float* ob = out + pixin + kq * 4;
  const int colb = lane & 15;
#pragma unroll
  for (int r = 0; r < 4; ++r) {
    ob[((b*64 +      colb) << 14) + r] = acc0[r];
    ob[((b*64 + 16 + colb) << 14) + r] = acc1[r];
    ob[((b*64 + 32 + colb) << 14) + r] = acc2[r];
    ob[((b*64 + 48 + colb) << 14) + r] = acc3[r];
  }
}

extern "C" void kernel_launch(void* const* d_in, const int* in_sizes, int n_in,
                              void* d_out, int out_size, void* d_ws, size_t ws_size,
                              hipStream_t stream) {
  const float* x     = (const float*)d_in[0];
  const float* w_off = (const float*)d_in[1];
  const float* w_def = (const float*)d_in[2];
  float* out = (float*)d_out;

  char* ws = (char*)d_ws;
  ushort* xt     = (ushort*)ws;
  float*  off    = (float*)(ws + XT_BYTES);
  ushort* pk_def = (ushort*)(ws + XT_BYTES + OFF_BYTES);
  ushort* pk_off = (ushort*)(ws + XT_BYTES + OFF_BYTES + PKDEF_BYTES);

  transpose_cast<<<1024, 256, 0, stream>>>(x, xt);
  prep_pack<<<32, 256, 0, stream>>>(w_off, w_def, pk_def, pk_off);
  offs_conv_mfma<<<512, 512, 0, stream>>>(xt, pk_off, off);
  deform_main_mfma<<<512, 512, 0, stream>>>(xt, pk_def, off, out);
}

// Round 4
// 82.326 us; speedup vs baseline: 22.7829x; 1.0280x over previous
//
#include <hip/hip_runtime.h>
#include <hip/hip_bf16.h>

typedef short bf16x8 __attribute__((ext_vector_type(8)));
typedef float f32x4  __attribute__((ext_vector_type(4)));

#define Bn 4
#define Cn 64
#define Hn 128
#define Wn 128
#define On 64
#define HWn 16384

// ws layout (bytes):
//   xt     [B][H][W][C] bf16   @ 0
//   off    [B][36][H][W] f32   @ XT_BYTES
//   pk_def [18][4][64][8] bf16 @ XT+OFF        B-frags, main conv
//   pk_off [18][3][64][8] bf16 @ XT+OFF+PKDEF  B-frags, offset conv
#define XT_BYTES    (Bn*HWn*Cn*2)
#define OFF_BYTES   (Bn*36*HWn*4)
#define PKDEF_BYTES (18*4*64*8*2)

static __device__ __forceinline__ unsigned pk_bf16(float lo, float hi) {
  union { __hip_bfloat162 h; unsigned u; } cv;
  cv.h = __float22bfloat162_rn(make_float2(lo, hi));
  return cv.u;
}
static __device__ __forceinline__ float blo(unsigned u) { return __uint_as_float(u << 16); }
static __device__ __forceinline__ float bhi(unsigned u) { return __uint_as_float(u & 0xffff0000u); }

// ---- x: NCHW f32 -> NHWC bf16, LDS-tiled transpose (64 pix x 64 ch per block)
__global__ __launch_bounds__(256) void transpose_cast(const float* __restrict__ x,
                                                      ushort* __restrict__ xt) {
  __shared__ float tile[64][65];
  const int t = threadIdx.x;
  const int blk = blockIdx.x;            // 1024 = B * (HW/64)
  const int b = blk >> 8;
  const int pix0 = (blk & 255) * 64;
  const float* xb = x + (b * Cn) * HWn + pix0;
#pragma unroll
  for (int q = 0; q < 16; ++q) {
    int idx = q * 256 + t;
    int c = idx >> 6, p = idx & 63;
    tile[c][p] = xb[c * HWn + p];
  }
  __syncthreads();
  const int p = t >> 2, cg = t & 3;
  unsigned u[8];
#pragma unroll
  for (int j = 0; j < 8; ++j)
    u[j] = pk_bf16(tile[cg * 16 + 2 * j][p], tile[cg * 16 + 2 * j + 1][p]);
  ushort* dst = xt + ((b * HWn + pix0 + p) * 64 + cg * 16);
  uint4 v0 = {u[0], u[1], u[2], u[3]}, v1 = {u[4], u[5], u[6], u[7]};
  *(uint4*)dst = v0;
  *(uint4*)(dst + 8) = v1;
}

// ---- pack weights as MFMA B-fragments (K-slice = 32 channels)
__global__ __launch_bounds__(256) void prep_pack(const float* __restrict__ w_off,
                                                 const float* __restrict__ w_def,
                                                 ushort* __restrict__ pk_def,
                                                 ushort* __restrict__ pk_off) {
  const int t = blockIdx.x * 256 + threadIdx.x;
  if (t < 4608) {                        // 18*4*64
    int lane = t & 63, oc = (t >> 6) & 3, s = t >> 8;
    int g = s / 9, k = s % 9;
    int o = oc * 16 + (lane & 15);
    int cb = g * 32 + (lane >> 4) * 8;
    unsigned u[4];
#pragma unroll
    for (int j = 0; j < 4; ++j)
      u[j] = pk_bf16(w_def[(o * Cn + cb + 2 * j) * 9 + k],
                     w_def[(o * Cn + cb + 2 * j + 1) * 9 + k]);
    uint4 v = {u[0], u[1], u[2], u[3]};
    *(uint4*)(pk_def + t * 8) = v;
  } else if (t < 8064) {                 // + 18*3*64
    int t2 = t - 4608;
    int lane = t2 & 63, r = t2 >> 6;     // r = s*3 + oc
    int oc = r % 3, s = r / 3;
    int k = s >> 1, chalf = s & 1;
    int o = oc * 16 + (lane & 15);
    int cb = chalf * 32 + (lane >> 4) * 8;
    unsigned u[4];
#pragma unroll
    for (int j = 0; j < 4; ++j) {
      float lo = (o < 36) ? w_off[(o * Cn + cb + 2 * j) * 9 + k] : 0.f;
      float hi = (o < 36) ? w_off[(o * Cn + cb + 2 * j + 1) * 9 + k] : 0.f;
      u[j] = pk_bf16(lo, hi);
    }
    uint4 v = {u[0], u[1], u[2], u[3]};
    *(uint4*)(pk_off + (r * 64 + lane) * 8) = v;
  }
}

// ---- offset conv via MFMA: M=16 pix/wave, N=48 (36 used), K=576
// XCD swizzle + depth-2 A-load pipeline.
__global__ __launch_bounds__(512, 4) void offs_conv_mfma(const ushort* __restrict__ xt,
                                                         const ushort* __restrict__ pk_off,
                                                         float* __restrict__ off) {
  const int lane = threadIdx.x & 63;
  const int wid = threadIdx.x >> 6;
  int bid = blockIdx.x;
  bid = (bid & 7) * 64 + (bid >> 3);            // 512 blocks, 512%8==0 -> bijective
  const int gp0 = bid * 128 + wid * 16;
  const int b = gp0 >> 14;
  const int pixin = gp0 & 16383;
  const int h = pixin >> 7;
  const int p = lane & 15, kq = lane >> 4;
  const int w_ = (pixin & 127) + p;

  f32x4 acc0 = {0,0,0,0}, acc1 = {0,0,0,0}, acc2 = {0,0,0,0};
  const bf16x8* pB = (const bf16x8*)pk_off;

  uint4 av[2];
#define OLOADA(s, dst) {                                                      \
    const int k = (s) >> 1, chalf = (s) & 1;                                  \
    int y = h + k / 3 - 1, xx = w_ + k % 3 - 1;                               \
    bool valid = ((unsigned)y < 128u) && ((unsigned)xx < 128u);               \
    int yc = min(max(y, 0), 127), xc = min(max(xx, 0), 127);                  \
    uint4 t_ = *(const uint4*)(xt + (((b << 14) + (yc << 7) + xc) << 6)       \
                               + chalf * 32 + kq * 8);                        \
    if (!valid) { t_.x = 0; t_.y = 0; t_.z = 0; t_.w = 0; }                   \
    dst = t_; }

  OLOADA(0, av[0])
#pragma unroll
  for (int s = 0; s < 18; ++s) {
    if (s + 1 < 18) OLOADA(s + 1, av[(s + 1) & 1])
    union { uint4 u; bf16x8 v; } A; A.u = av[s & 1];
    acc0 = __builtin_amdgcn_mfma_f32_16x16x32_bf16(A.v, pB[(s*3 + 0)*64 + lane], acc0, 0,0,0);
    acc1 = __builtin_amdgcn_mfma_f32_16x16x32_bf16(A.v, pB[(s*3 + 1)*64 + lane], acc1, 0,0,0);
    acc2 = __builtin_amdgcn_mfma_f32_16x16x32_bf16(A.v, pB[(s*3 + 2)*64 + lane], acc2, 0,0,0);
  }
#undef OLOADA

  float* ob = off + pixin + kq * 4;
  const int colb = lane & 15;
#pragma unroll
  for (int r = 0; r < 4; ++r) {
    ob[((b*36 +      colb) << 14) + r] = acc0[r];
    ob[((b*36 + 16 + colb) << 14) + r] = acc1[r];
    if (colb < 4) ob[((b*36 + 32 + colb) << 14) + r] = acc2[r];
  }
}

// ---- main deformable conv via MFMA: M=16 pix/wave, N=64, K=576 (g,k,c)
// XCD swizzle + full offset preload + depth-2 gather pipeline.
__global__ __launch_bounds__(512, 4) void deform_main_mfma(const ushort* __restrict__ xt,
                                                           const ushort* __restrict__ pk_def,
                                                           const float* __restrict__ off,
                                                           float* __restrict__ out) {
  const int lane = threadIdx.x & 63;
  const int wid = threadIdx.x >> 6;
  int bid = blockIdx.x;
  bid = (bid & 7) * 64 + (bid >> 3);            // XCD swizzle
  const int gp0 = bid * 128 + wid * 16;
  const int b = gp0 >> 14;
  const int pixin = gp0 & 16383;
  const int h = pixin >> 7;
  const int p = lane & 15, kq = lane >> 4;
  const int w_ = (pixin & 127) + p;
  const int imgb = b << 14;

  // preload ALL 36 offset channels for this lane's pixel (coalesced, L2-hot)
  const float* offb = off + ((b * 36) << 14) + pixin + p;
  float offv[36];
#pragma unroll
  for (int j = 0; j < 36; ++j) offv[j] = offb[j << 14];

  f32x4 acc0={0,0,0,0}, acc1={0,0,0,0}, acc2={0,0,0,0}, acc3={0,0,0,0};
  const bf16x8* pB = (const bf16x8*)pk_def;

  struct Stage { float w00, w01, w10, w11; uint4 c00, c01, c10, c11; };
  Stage st[2];

#define DPREP(s, S) {                                                          \
    const int g = (s) / 9, k = (s) % 9;                                        \
    const int cb = g * 32 + kq * 8;                                            \
    float py = offv[2*(s)]   + (float)(h  + k / 3 - 1);                        \
    float px = offv[2*(s)+1] + (float)(w_ + k % 3 - 1);                        \
    float fy = floorf(py), fx = floorf(px);                                    \
    int y0 = (int)fy, x0 = (int)fx;                                            \
    float dy = py - fy, dx = px - fx;                                          \
    bool vy0 = (y0 >= 0) && (y0 < Hn);                                         \
    bool vy1 = (y0 >= -1) && (y0 < Hn - 1);                                    \
    bool vx0 = (x0 >= 0) && (x0 < Wn);                                         \
    bool vx1 = (x0 >= -1) && (x0 < Wn - 1);                                    \
    float omdy = 1.f - dy, omdx = 1.f - dx;                                    \
    S.w00 = (vy0 && vx0) ? omdy * omdx : 0.f;                                  \
    S.w01 = (vy0 && vx1) ? omdy * dx   : 0.f;                                  \
    S.w10 = (vy1 && vx0) ? dy * omdx   : 0.f;                                  \
    S.w11 = (vy1 && vx1) ? dy * dx     : 0.f;                                  \
    int iy0 = min(max(y0, 0), Hn - 1), iy1 = min(max(y0 + 1, 0), Hn - 1);      \
    int ix0 = min(max(x0, 0), Wn - 1), ix1 = min(max(x0 + 1, 0), Wn - 1);      \
    int rb0 = imgb + (iy0 << 7), rb1 = imgb + (iy1 << 7);                      \
    S.c00 = *(const uint4*)(xt + ((rb0 + ix0) << 6) + cb);                     \
    S.c01 = *(const uint4*)(xt + ((rb0 + ix1) << 6) + cb);                     \
    S.c10 = *(const uint4*)(xt + ((rb1 + ix0) << 6) + cb);                     \
    S.c11 = *(const uint4*)(xt + ((rb1 + ix1) << 6) + cb); }

  DPREP(0, st[0])
#pragma unroll
  for (int s = 0; s < 18; ++s) {
    if (s + 1 < 18) DPREP(s + 1, st[(s + 1) & 1])
    Stage& S = st[s & 1];
    unsigned au[4];
#define BILC(comp, idx)                                                               \
    { float l = S.w00 * blo(S.c00.comp); l = fmaf(S.w01, blo(S.c01.comp), l);         \
      l = fmaf(S.w10, blo(S.c10.comp), l); l = fmaf(S.w11, blo(S.c11.comp), l);       \
      float hh = S.w00 * bhi(S.c00.comp); hh = fmaf(S.w01, bhi(S.c01.comp), hh);      \
      hh = fmaf(S.w10, bhi(S.c10.comp), hh); hh = fmaf(S.w11, bhi(S.c11.comp), hh);   \
      au[idx] = pk_bf16(l, hh); }
    BILC(x, 0) BILC(y, 1) BILC(z, 2) BILC(w, 3)
#undef BILC
    union { uint4 u; bf16x8 v; } A;
    A.u.x = au[0]; A.u.y = au[1]; A.u.z = au[2]; A.u.w = au[3];

    acc0 = __builtin_amdgcn_mfma_f32_16x16x32_bf16(A.v, pB[(s*4 + 0)*64 + lane], acc0, 0,0,0);
    acc1 = __builtin_amdgcn_mfma_f32_16x16x32_bf16(A.v, pB[(s*4 + 1)*64 + lane], acc1, 0,0,0);
    acc2 = __builtin_amdgcn_mfma_f32_16x16x32_bf16(A.v, pB[(s*4 + 2)*64 + lane], acc2, 0,0,0);
    acc3 = __builtin_amdgcn_mfma_f32_16x16x32_bf16(A.v, pB[(s*4 + 3)*64 + lane], acc3, 0,0,0);
  }
#undef DPREP

  float* ob = out + pixin + kq * 4;
  const int colb = lane & 15;
#pragma unroll
  for (int r = 0; r < 4; ++r) {
    ob[((b*64 +      colb) << 14) + r] = acc0[r];
    ob[((b*64 + 16 + colb) << 14) + r] = acc1[r];
    ob[((b*64 + 32 + colb) << 14) + r] = acc2[r];
    ob[((b*64 + 48 + colb) << 14) + r] = acc3[r];
  }
}

extern "C" void kernel_launch(void* const* d_in, const int* in_sizes, int n_in,
                              void* d_out, int out_size, void* d_ws, size_t ws_size,
                              hipStream_t stream) {
  const float* x     = (const float*)d_in[0];
  const float* w_off = (const float*)d_in[1];
  const float* w_def = (const float*)d_in[2];
  float* out = (float*)d_out;

  char* ws = (char*)d_ws;
  ushort* xt     = (ushort*)ws;
  float*  off    = (float*)(ws + XT_BYTES);
  ushort* pk_def = (ushort*)(ws + XT_BYTES + OFF_BYTES);
  ushort* pk_off = (ushort*)(ws + XT_BYTES + OFF_BYTES + PKDEF_BYTES);

  transpose_cast<<<1024, 256, 0, stream>>>(x, xt);
  prep_pack<<<32, 256, 0, stream>>>(w_off, w_def, pk_def, pk_off);
  offs_conv_mfma<<<512, 512, 0, stream>>>(xt, pk_off, off);
  deform_main_mfma<<<512, 512, 0, stream>>>(xt, pk_def, off, out);
}